// Round 1
// baseline (8080.138 us; speedup 1.0000x reference)
//
#include <hip/hip_runtime.h>
#include <cstdint>
#include <cstddef>

// ---------------------------------------------------------------- constants
#define NB   64      // batch
#define C192 192
#define NPIX 169     // 13*13
#define WD   13
#define NH   8
#define HD   24      // head dim
#define SEQM (NPIX*NB)   // 10816 GEMM rows

// ---------------------------------------------------------------- xcorr
// depthwise VALID correlation: x (B*C,31,31) * z (B*C,7,7) -> (B*C,25,25)
__global__ __launch_bounds__(256) void xcorr_kernel(
    const float* __restrict__ x, const float* __restrict__ z,
    float* __restrict__ out)
{
    int bc = blockIdx.x;
    const float* xin = x + (size_t)bc * 961;
    const float* zin = z + (size_t)bc * 49;
    float* o = out + (size_t)bc * 625;
    __shared__ float xs[961];
    __shared__ float zs[49];
    for (int i = threadIdx.x; i < 961; i += 256) xs[i] = xin[i];
    if (threadIdx.x < 49) zs[threadIdx.x] = zin[threadIdx.x];
    __syncthreads();
    for (int p = threadIdx.x; p < 625; p += 256) {
        int oy = p / 25, ox = p % 25;
        float acc = 0.f;
        #pragma unroll
        for (int ky = 0; ky < 7; ++ky) {
            #pragma unroll
            for (int kx = 0; kx < 7; ++kx)
                acc = fmaf(xs[(oy + ky) * 31 + ox + kx], zs[ky * 7 + kx], acc);
        }
        o[p] = acc;
    }
}

// ---------------------------------------------------------------- conv 3x3 stride2 pad1 + BN + ReLU
// in (64,CIN,25,25) -> out (64,192,169)   (b,c,n layout)
template<int CIN>
__global__ __launch_bounds__(192) void conv_s2_bn_relu(
    const float* __restrict__ in, const float* __restrict__ w,
    const float* __restrict__ bn_g, const float* __restrict__ bn_b,
    const float* __restrict__ bn_m, const float* __restrict__ bn_v,
    float* __restrict__ out)
{
    constexpr int CO_T = 16;
    const int b   = blockIdx.x;
    const int co0 = blockIdx.y * CO_T;
    const int t   = threadIdx.x;
    __shared__ float xs[4 * 729];  // 4 padded 27x27 planes
    float acc[CO_T];
    #pragma unroll
    for (int i = 0; i < CO_T; ++i) acc[i] = 0.f;
    int py = 0, px = 0;
    if (t < NPIX) { py = (t / WD) * 2; px = (t % WD) * 2; }
    const float* inb = in + (size_t)b * CIN * 625;

    for (int c0 = 0; c0 < CIN; c0 += 4) {
        __syncthreads();
        for (int i = t; i < 4 * 729; i += 192) {
            int pl = i / 729, pp = i % 729;
            int y = pp / 27, x = pp % 27;
            float v = 0.f;
            if (y >= 1 && y <= 25 && x >= 1 && x <= 25)
                v = inb[(size_t)(c0 + pl) * 625 + (y - 1) * 25 + (x - 1)];
            xs[i] = v;
        }
        __syncthreads();
        if (t < NPIX) {
            #pragma unroll
            for (int pl = 0; pl < 4; ++pl) {
                float xv[9];
                const float* xp = xs + pl * 729 + py * 27 + px;
                #pragma unroll
                for (int ky = 0; ky < 3; ++ky) {
                    #pragma unroll
                    for (int kx = 0; kx < 3; ++kx)
                        xv[ky * 3 + kx] = xp[ky * 27 + kx];
                }
                #pragma unroll
                for (int co = 0; co < CO_T; ++co) {
                    const float* wc = w + ((size_t)(co0 + co) * CIN + (c0 + pl)) * 9;
                    #pragma unroll
                    for (int k = 0; k < 9; ++k)
                        acc[co] = fmaf(xv[k], wc[k], acc[co]);
                }
            }
        }
    }
    if (t < NPIX) {
        #pragma unroll
        for (int co = 0; co < CO_T; ++co) {
            int c = co0 + co;
            float inv = rsqrtf(bn_v[c] + 1e-5f);
            float sc  = bn_g[c] * inv;
            float sh  = bn_b[c] - bn_m[c] * sc;
            float r   = fmaf(acc[co], sc, sh);
            out[((size_t)b * C192 + c) * NPIX + t] = fmaxf(r, 0.f);
        }
    }
}

// ---------------------------------------------------------------- conv 3x3 stride1 pad1 + bias
// in (64,192,169) -> out (64,Cout,169), Cout = gridDim.y * CO_T
template<int CO_T>
__global__ __launch_bounds__(192) void conv_s1_bias(
    const float* __restrict__ in, const float* __restrict__ w,
    const float* __restrict__ bias, float* __restrict__ out)
{
    const int b    = blockIdx.x;
    const int co0  = blockIdx.y * CO_T;
    const int Cout = gridDim.y * CO_T;
    const int t    = threadIdx.x;
    __shared__ float xs[4 * 225];  // 4 padded 15x15 planes
    float acc[CO_T];
    #pragma unroll
    for (int i = 0; i < CO_T; ++i) acc[i] = 0.f;
    int py = 0, px = 0;
    if (t < NPIX) { py = t / WD; px = t % WD; }
    const float* inb = in + (size_t)b * C192 * NPIX;

    for (int c0 = 0; c0 < C192; c0 += 4) {
        __syncthreads();
        for (int i = t; i < 4 * 225; i += 192) {
            int pl = i / 225, pp = i % 225;
            int y = pp / 15, x = pp % 15;
            float v = 0.f;
            if (y >= 1 && y <= 13 && x >= 1 && x <= 13)
                v = inb[(size_t)(c0 + pl) * NPIX + (y - 1) * WD + (x - 1)];
            xs[i] = v;
        }
        __syncthreads();
        if (t < NPIX) {
            #pragma unroll
            for (int pl = 0; pl < 4; ++pl) {
                float xv[9];
                const float* xp = xs + pl * 225;
                #pragma unroll
                for (int ky = 0; ky < 3; ++ky) {
                    #pragma unroll
                    for (int kx = 0; kx < 3; ++kx)
                        xv[ky * 3 + kx] = xp[(py + ky) * 15 + px + kx];
                }
                #pragma unroll
                for (int co = 0; co < CO_T; ++co) {
                    const float* wc = w + ((size_t)(co0 + co) * C192 + (c0 + pl)) * 9;
                    #pragma unroll
                    for (int k = 0; k < 9; ++k)
                        acc[co] = fmaf(xv[k], wc[k], acc[co]);
                }
            }
        }
    }
    if (t < NPIX) {
        #pragma unroll
        for (int co = 0; co < CO_T; ++co) {
            int c = co0 + co;
            out[((size_t)b * Cout + c) * NPIX + t] = acc[co] + bias[c];
        }
    }
}

// ---------------------------------------------------------------- GroupNorm(32) + ReLU, in-place on (64,192,169)
__global__ __launch_bounds__(256) void gn_relu_kernel(
    float* __restrict__ x, const float* __restrict__ g, const float* __restrict__ b)
{
    const int blk = blockIdx.x;          // b*32 + grp
    const int bb = blk / 32, grp = blk % 32;
    float* xp = x + ((size_t)bb * C192 + grp * 6) * NPIX;
    const int N = 6 * NPIX;              // 1014
    const int t = threadIdx.x;
    float vals[4];
    float s = 0.f, s2 = 0.f;
    #pragma unroll
    for (int i = 0; i < 4; ++i) {
        int idx = t + i * 256;
        float v = (idx < N) ? xp[idx] : 0.f;
        vals[i] = v; s += v; s2 += v * v;
    }
    #pragma unroll
    for (int o = 32; o; o >>= 1) { s += __shfl_down(s, o); s2 += __shfl_down(s2, o); }
    __shared__ float redS[4], redS2[4];
    int wid = t >> 6, lane = t & 63;
    if (lane == 0) { redS[wid] = s; redS2[wid] = s2; }
    __syncthreads();
    float S  = redS[0] + redS[1] + redS[2] + redS[3];
    float S2 = redS2[0] + redS2[1] + redS2[2] + redS2[3];
    float mean = S / (float)N;
    float var  = S2 / (float)N - mean * mean;
    float inv  = rsqrtf(var + 1e-5f);
    #pragma unroll
    for (int i = 0; i < 4; ++i) {
        int idx = t + i * 256;
        if (idx < N) {
            int ch = grp * 6 + idx / NPIX;
            float y = (vals[i] - mean) * inv * g[ch] + b[ch];
            xp[idx] = fmaxf(y, 0.f);
        }
    }
}

// ---------------------------------------------------------------- GEMM: C[M,N] = A[M,K] @ W[N,K]^T + bias (+ReLU)
template<bool RELU>
__global__ __launch_bounds__(256) void gemm_nt(
    const float* __restrict__ A, const float* __restrict__ W,
    const float* __restrict__ bias, float* __restrict__ C,
    int M, int N, int K)
{
    const int BK = 32;
    __shared__ float As[BK][69];
    __shared__ float Ws[BK][69];
    const int mb = blockIdx.x, nb = blockIdx.y;
    const int t = threadIdx.x;
    const int tx = t % 16, ty = t / 16;
    float acc[4][4] = {};
    for (int k0 = 0; k0 < K; k0 += BK) {
        __syncthreads();
        {
            int r = t / 8, kv = (t % 8) * 4;
            const float4 a0 = *(const float4*)&A[(size_t)(mb * 64 + r) * K + k0 + kv];
            const float4 a1 = *(const float4*)&A[(size_t)(mb * 64 + r + 32) * K + k0 + kv];
            As[kv + 0][r] = a0.x; As[kv + 1][r] = a0.y; As[kv + 2][r] = a0.z; As[kv + 3][r] = a0.w;
            As[kv + 0][r + 32] = a1.x; As[kv + 1][r + 32] = a1.y; As[kv + 2][r + 32] = a1.z; As[kv + 3][r + 32] = a1.w;
            const float4 w0 = *(const float4*)&W[(size_t)(nb * 64 + r) * K + k0 + kv];
            const float4 w1 = *(const float4*)&W[(size_t)(nb * 64 + r + 32) * K + k0 + kv];
            Ws[kv + 0][r] = w0.x; Ws[kv + 1][r] = w0.y; Ws[kv + 2][r] = w0.z; Ws[kv + 3][r] = w0.w;
            Ws[kv + 0][r + 32] = w1.x; Ws[kv + 1][r + 32] = w1.y; Ws[kv + 2][r + 32] = w1.z; Ws[kv + 3][r + 32] = w1.w;
        }
        __syncthreads();
        #pragma unroll
        for (int kk = 0; kk < BK; ++kk) {
            float a[4], w[4];
            #pragma unroll
            for (int i = 0; i < 4; ++i) a[i] = As[kk][ty + i * 16];
            #pragma unroll
            for (int j = 0; j < 4; ++j) w[j] = Ws[kk][tx + j * 16];
            #pragma unroll
            for (int i = 0; i < 4; ++i)
                #pragma unroll
                for (int j = 0; j < 4; ++j)
                    acc[i][j] = fmaf(a[i], w[j], acc[i][j]);
        }
    }
    #pragma unroll
    for (int i = 0; i < 4; ++i) {
        #pragma unroll
        for (int j = 0; j < 4; ++j) {
            int m = mb * 64 + ty + i * 16;
            int n = nb * 64 + tx + j * 16;
            float v = acc[i][j] + bias[n];
            if (RELU) v = fmaxf(v, 0.f);
            C[(size_t)m * N + n] = v;
        }
    }
}

// ---------------------------------------------------------------- add positional embedding: dst[n,b,c] = src[n,b,c] + pos[n,c]
__global__ __launch_bounds__(256) void addpos_kernel(
    const float* __restrict__ src, const float* __restrict__ row_e,
    const float* __restrict__ col_e, float* __restrict__ dst)
{
    const int total = NPIX * NB * C192;
    int i = blockIdx.x * 256 + threadIdx.x;
    if (i >= total) return;
    int c = i % C192;
    int n = i / (C192 * NB);
    float p = (c < 96) ? col_e[(n % WD) * 96 + c] : row_e[(n / WD) * 96 + (c - 96)];
    dst[i] = src[i] + p;
}

// ---------------------------------------------------------------- masked attention, flash-style, one thread per query row
__global__ __launch_bounds__(192) void attn_kernel(
    const float* __restrict__ Q, const float* __restrict__ K,
    const float* __restrict__ V, const int* __restrict__ mask_size,
    float* __restrict__ O)
{
    const int bh = blockIdx.x;   // b*8 + h
    const int b = bh / NH, h = bh % NH;
    __shared__ float Ks[NPIX][HD];
    __shared__ float Vs[NPIX][HD];
    const int t = threadIdx.x;
    for (int i = t; i < NPIX * HD; i += 192) {
        int n = i / HD, d = i % HD;
        size_t base = ((size_t)n * NB + b) * C192 + h * HD + d;
        Ks[n][d] = K[base];
        Vs[n][d] = V[base];
    }
    __syncthreads();
    if (t < NPIX) {
        float q[HD];
        size_t qbase = ((size_t)t * NB + b) * C192 + h * HD;
        #pragma unroll
        for (int d = 0; d < HD; ++d) q[d] = Q[qbase + d];
        const int ms2 = mask_size[0] / 2;
        const int ri = t / WD, ci = t % WD;
        const int r0 = max(ri - ms2, 0), r1 = min(ri + ms2, WD - 1);
        const int c0 = max(ci - ms2, 0), c1 = min(ci + ms2, WD - 1);
        float mx = -1e30f, sum = 0.f;
        float o[HD];
        #pragma unroll
        for (int d = 0; d < HD; ++d) o[d] = 0.f;
        const float scale = 0.20412414523193150f;   // 24^-0.5
        for (int rm = r0; rm <= r1; ++rm) {
            for (int cm = c0; cm <= c1; ++cm) {
                int m = rm * WD + cm;
                float s = 0.f;
                #pragma unroll
                for (int d = 0; d < HD; ++d) s = fmaf(q[d], Ks[m][d], s);
                s *= scale;
                if (s > mx) {
                    float f = expf(mx - s);
                    sum *= f;
                    #pragma unroll
                    for (int d = 0; d < HD; ++d) o[d] *= f;
                    mx = s;
                }
                float p = expf(s - mx);
                sum += p;
                #pragma unroll
                for (int d = 0; d < HD; ++d) o[d] = fmaf(p, Vs[m][d], o[d]);
            }
        }
        float r = 1.f / sum;
        #pragma unroll
        for (int d = 0; d < HD; ++d) O[qbase + d] = o[d] * r;
    }
}

// ---------------------------------------------------------------- fused residual-add + LayerNorm(192), in-place: x = LN(x + a)
__global__ __launch_bounds__(256) void add_ln_kernel(
    float* __restrict__ x, const float* __restrict__ a,
    const float* __restrict__ g, const float* __restrict__ b)
{
    const int row = blockIdx.x * 4 + (threadIdx.x >> 6);
    const int lane = threadIdx.x & 63;
    float* xp = x + (size_t)row * C192;
    const float* ap = a + (size_t)row * C192;
    float v[3];
    float s = 0.f, s2 = 0.f;
    #pragma unroll
    for (int i = 0; i < 3; ++i) {
        float t = xp[lane + i * 64] + ap[lane + i * 64];
        v[i] = t; s += t; s2 += t * t;
    }
    #pragma unroll
    for (int o = 32; o; o >>= 1) { s += __shfl_down(s, o); s2 += __shfl_down(s2, o); }
    s = __shfl(s, 0); s2 = __shfl(s2, 0);
    float mean = s * (1.f / 192.f);
    float var  = s2 * (1.f / 192.f) - mean * mean;
    float inv  = rsqrtf(var + 1e-5f);
    #pragma unroll
    for (int i = 0; i < 3; ++i) {
        int c = lane + i * 64;
        xp[c] = (v[i] - mean) * inv * g[c] + b[c];
    }
}

// ---------------------------------------------------------------- transposes between (64,192,169) and (169,64,192)
__global__ __launch_bounds__(256) void transpose_cn_nc(
    const float* __restrict__ src, float* __restrict__ dst)
{
    __shared__ float tile[32][33];
    const int b = blockIdx.z;
    const int c0 = blockIdx.x * 32, n0 = blockIdx.y * 32;
    const int tx = threadIdx.x % 32, ty = threadIdx.x / 32;
    #pragma unroll
    for (int i = 0; i < 32; i += 8) {
        int c = c0 + ty + i, n = n0 + tx;
        if (c < C192 && n < NPIX) tile[ty + i][tx] = src[((size_t)b * C192 + c) * NPIX + n];
    }
    __syncthreads();
    #pragma unroll
    for (int i = 0; i < 32; i += 8) {
        int n = n0 + ty + i, c = c0 + tx;
        if (n < NPIX && c < C192) dst[((size_t)n * NB + b) * C192 + c] = tile[tx][ty + i];
    }
}

__global__ __launch_bounds__(256) void transpose_nc_cn(
    const float* __restrict__ src, float* __restrict__ dst)
{
    __shared__ float tile[32][33];
    const int b = blockIdx.z;
    const int n0 = blockIdx.x * 32, c0 = blockIdx.y * 32;
    const int tx = threadIdx.x % 32, ty = threadIdx.x / 32;
    #pragma unroll
    for (int i = 0; i < 32; i += 8) {
        int n = n0 + ty + i, c = c0 + tx;
        if (n < NPIX && c < C192) tile[ty + i][tx] = src[((size_t)n * NB + b) * C192 + c];
    }
    __syncthreads();
    #pragma unroll
    for (int i = 0; i < 32; i += 8) {
        int c = c0 + ty + i, n = n0 + tx;
        if (c < C192 && n < NPIX) dst[((size_t)b * C192 + c) * NPIX + n] = tile[tx][ty + i];
    }
}

// ---------------------------------------------------------------- launch
extern "C" void kernel_launch(void* const* d_in, const int* in_sizes, int n_in,
                              void* d_out, int out_size, void* d_ws, size_t ws_size,
                              hipStream_t stream)
{
    // inputs (setup_inputs dict order)
    const float* x0 = (const float*)d_in[0];
    const float* x1 = (const float*)d_in[1];
    const float* x2 = (const float*)d_in[2];
    const float* z0 = (const float*)d_in[3];
    const float* z1 = (const float*)d_in[4];
    const float* z2 = (const float*)d_in[5];
    const float* conv1_w = (const float*)d_in[6];
    const float* conv3_w = (const float*)d_in[7];
    const float* conv2_w = (const float*)d_in[8];
    const float* bn1_g = (const float*)d_in[9];
    const float* bn1_b = (const float*)d_in[10];
    const float* bn1_m = (const float*)d_in[11];
    const float* bn1_v = (const float*)d_in[12];
    const float* bn2_g = (const float*)d_in[13];
    const float* bn2_b = (const float*)d_in[14];
    const float* bn2_m = (const float*)d_in[15];
    const float* bn2_v = (const float*)d_in[16];
    const float* bn3_g = (const float*)d_in[17];
    const float* bn3_b = (const float*)d_in[18];
    const float* bn3_m = (const float*)d_in[19];
    const float* bn3_v = (const float*)d_in[20];
    const float* row_embed = (const float*)d_in[21];
    const float* col_embed = (const float*)d_in[22];
    const float* t_wq = (const float*)d_in[23];
    const float* t_bq = (const float*)d_in[24];
    const float* t_wk = (const float*)d_in[25];
    const float* t_bk = (const float*)d_in[26];
    const float* t_wv = (const float*)d_in[27];
    const float* t_bv = (const float*)d_in[28];
    const float* t_wo = (const float*)d_in[29];
    const float* t_bo = (const float*)d_in[30];
    const float* t_ln1_g = (const float*)d_in[31];
    const float* t_ln1_b = (const float*)d_in[32];
    const float* t_ln2_g = (const float*)d_in[33];
    const float* t_ln2_b = (const float*)d_in[34];
    const float* t_ff1_w = (const float*)d_in[35];
    const float* t_ff1_b = (const float*)d_in[36];
    const float* t_ff2_w = (const float*)d_in[37];
    const float* t_ff2_b = (const float*)d_in[38];
    const float* convloc_w = (const float*)d_in[39];
    const float* convloc_b = (const float*)d_in[40];
    const float* convloc_gn_g = (const float*)d_in[41];
    const float* convloc_gn_b = (const float*)d_in[42];
    const float* loc_out_w = (const float*)d_in[43];
    const float* loc_out_b = (const float*)d_in[44];
    const float* convcls_w = (const float*)d_in[45];
    const float* convcls_b = (const float*)d_in[46];
    const float* convcls_gn_g = (const float*)d_in[47];
    const float* convcls_gn_b = (const float*)d_in[48];
    const float* cls1_w = (const float*)d_in[49];
    const float* cls1_b = (const float*)d_in[50];
    const float* cls2_w = (const float*)d_in[51];
    const float* cls2_b = (const float*)d_in[52];
    const int*   mask_size = (const int*)d_in[53];
    float* out = (float*)d_out;

    // workspace layout (floats)
    const size_t SZ_X = (size_t)NB * 384 * 625;   // 15,360,000 (xcorr scratch / ffn hidden)
    const size_t SZ_S = (size_t)NPIX * NB * C192; // 2,076,672
    float* ws   = (float*)d_ws;
    float* Abuf = ws;
    float* res1 = Abuf + SZ_X;
    float* res2 = res1 + SZ_S;
    float* outb = res2 + SZ_S;
    float* qb   = outb + SZ_S;
    float* kb   = qb + SZ_S;
    float* vb   = kb + SZ_S;
    float* ob   = vb + SZ_S;
    float* resT = ob + SZ_S;
    float* y0   = resT + SZ_S;
    float* y1   = y0 + SZ_S;

    const dim3 tgrid_cn(6, 6, NB), tgrid_nc(6, 6, NB);

    // ---------------- stage A: xcorr -> conv s2 -> BN -> ReLU (3 branches)
    xcorr_kernel<<<NB * 384, 256, 0, stream>>>(x0, z0, Abuf);
    conv_s2_bn_relu<384><<<dim3(NB, 12), 192, 0, stream>>>(Abuf, conv1_w, bn1_g, bn1_b, bn1_m, bn1_v, y0);
    transpose_cn_nc<<<tgrid_cn, 256, 0, stream>>>(y0, res1);

    xcorr_kernel<<<NB * 384, 256, 0, stream>>>(x1, z1, Abuf);
    conv_s2_bn_relu<384><<<dim3(NB, 12), 192, 0, stream>>>(Abuf, conv3_w, bn3_g, bn3_b, bn3_m, bn3_v, y0);
    transpose_cn_nc<<<tgrid_cn, 256, 0, stream>>>(y0, res2);

    xcorr_kernel<<<NB * 256, 256, 0, stream>>>(x2, z2, Abuf);
    conv_s2_bn_relu<256><<<dim3(NB, 12), 192, 0, stream>>>(Abuf, conv2_w, bn2_g, bn2_b, bn2_m, bn2_v, y0);
    transpose_cn_nc<<<tgrid_cn, 256, 0, stream>>>(y0, outb);

    // ---------------- transformer (2 cross-attention layers)
    const int addpos_grid = (NPIX * NB * C192 + 255) / 256;
    for (int li = 0; li < 2; ++li) {
        const float* mem = (li == 0) ? res1 : res2;
        const float* wq = t_wq + (size_t)li * C192 * C192;
        const float* wk = t_wk + (size_t)li * C192 * C192;
        const float* wv = t_wv + (size_t)li * C192 * C192;
        const float* wo = t_wo + (size_t)li * C192 * C192;
        const float* bq = t_bq + (size_t)li * C192;
        const float* bk = t_bk + (size_t)li * C192;
        const float* bv = t_bv + (size_t)li * C192;
        const float* bo = t_bo + (size_t)li * C192;

        addpos_kernel<<<addpos_grid, 256, 0, stream>>>(outb, row_embed, col_embed, qb);
        addpos_kernel<<<addpos_grid, 256, 0, stream>>>(mem,  row_embed, col_embed, kb);

        gemm_nt<false><<<dim3(SEQM / 64, 3), 256, 0, stream>>>(qb,  wq, bq, vb, SEQM, C192, C192); // Qh
        gemm_nt<false><<<dim3(SEQM / 64, 3), 256, 0, stream>>>(kb,  wk, bk, qb, SEQM, C192, C192); // Kh
        gemm_nt<false><<<dim3(SEQM / 64, 3), 256, 0, stream>>>(mem, wv, bv, kb, SEQM, C192, C192); // Vh

        attn_kernel<<<NB * NH, 192, 0, stream>>>(vb, qb, kb, mask_size, ob);

        gemm_nt<false><<<dim3(SEQM / 64, 3), 256, 0, stream>>>(ob, wo, bo, qb, SEQM, C192, C192);
        add_ln_kernel<<<SEQM / 4, 256, 0, stream>>>(outb, qb,
            t_ln1_g + (size_t)li * C192, t_ln1_b + (size_t)li * C192);

        gemm_nt<true><<<dim3(SEQM / 64, 12), 256, 0, stream>>>(outb,
            t_ff1_w + (size_t)li * 768 * C192, t_ff1_b + (size_t)li * 768, Abuf, SEQM, 768, C192);
        gemm_nt<false><<<dim3(SEQM / 64, 3), 256, 0, stream>>>(Abuf,
            t_ff2_w + (size_t)li * C192 * 768, t_ff2_b + (size_t)li * C192, qb, SEQM, C192, 768);
        add_ln_kernel<<<SEQM / 4, 256, 0, stream>>>(outb, qb,
            t_ln2_g + (size_t)li * C192, t_ln2_b + (size_t)li * C192);
    }

    // ---------------- back to (b,c,n) for the conv towers
    transpose_nc_cn<<<tgrid_nc, 256, 0, stream>>>(outb, resT);

    // ---------------- loc tower
    conv_s1_bias<16><<<dim3(NB, 12), 192, 0, stream>>>(resT, convloc_w + 0 * (size_t)C192 * C192 * 9, convloc_b + 0, y0);
    gn_relu_kernel<<<NB * 32, 256, 0, stream>>>(y0, convloc_gn_g + 0, convloc_gn_b + 0);
    conv_s1_bias<16><<<dim3(NB, 12), 192, 0, stream>>>(y0, convloc_w + 1 * (size_t)C192 * C192 * 9, convloc_b + C192, y1);
    gn_relu_kernel<<<NB * 32, 256, 0, stream>>>(y1, convloc_gn_g + C192, convloc_gn_b + C192);
    conv_s1_bias<16><<<dim3(NB, 12), 192, 0, stream>>>(y1, convloc_w + 2 * (size_t)C192 * C192 * 9, convloc_b + 2 * C192, y0);
    gn_relu_kernel<<<NB * 32, 256, 0, stream>>>(y0, convloc_gn_g + 2 * C192, convloc_gn_b + 2 * C192);
    conv_s1_bias<4><<<dim3(NB, 1), 192, 0, stream>>>(y0, loc_out_w, loc_out_b, out);   // (64,4,169)

    // ---------------- cls tower
    conv_s1_bias<16><<<dim3(NB, 12), 192, 0, stream>>>(resT, convcls_w + 0 * (size_t)C192 * C192 * 9, convcls_b + 0, y1);
    gn_relu_kernel<<<NB * 32, 256, 0, stream>>>(y1, convcls_gn_g + 0, convcls_gn_b + 0);
    conv_s1_bias<16><<<dim3(NB, 12), 192, 0, stream>>>(y1, convcls_w + 1 * (size_t)C192 * C192 * 9, convcls_b + C192, y0);
    gn_relu_kernel<<<NB * 32, 256, 0, stream>>>(y0, convcls_gn_g + C192, convcls_gn_b + C192);
    conv_s1_bias<16><<<dim3(NB, 12), 192, 0, stream>>>(y0, convcls_w + 2 * (size_t)C192 * C192 * 9, convcls_b + 2 * C192, y1);
    gn_relu_kernel<<<NB * 32, 256, 0, stream>>>(y1, convcls_gn_g + 2 * C192, convcls_gn_b + 2 * C192);
    conv_s1_bias<2><<<dim3(NB, 1), 192, 0, stream>>>(y1, cls1_w, cls1_b, out + (size_t)NB * 4 * NPIX);
    conv_s1_bias<1><<<dim3(NB, 1), 192, 0, stream>>>(y1, cls2_w, cls2_b, out + (size_t)NB * 6 * NPIX);
}

// Round 2
// 2509.099 us; speedup vs baseline: 3.2203x; 3.2203x over previous
//
#include <hip/hip_runtime.h>
#include <cstdint>
#include <cstddef>

// ---------------------------------------------------------------- constants
#define NB   64      // batch
#define C192 192
#define NPIX 169     // 13*13
#define WD   13
#define NH   8
#define HD   24      // head dim
#define SEQM (NPIX*NB)   // 10816 rows, ordering m = b*169 + pix

// ---------------------------------------------------------------- xcorr
// depthwise VALID correlation: x (B*C,31,31) * z (B*C,7,7) -> (B*C,25,25)
__global__ __launch_bounds__(256) void xcorr_kernel(
    const float* __restrict__ x, const float* __restrict__ z,
    float* __restrict__ out)
{
    int bc = blockIdx.x;
    const float* xin = x + (size_t)bc * 961;
    const float* zin = z + (size_t)bc * 49;
    float* o = out + (size_t)bc * 625;
    __shared__ float xs[961];
    __shared__ float zs[49];
    for (int i = threadIdx.x; i < 961; i += 256) xs[i] = xin[i];
    if (threadIdx.x < 49) zs[threadIdx.x] = zin[threadIdx.x];
    __syncthreads();
    for (int p = threadIdx.x; p < 625; p += 256) {
        int oy = p / 25, ox = p % 25;
        float acc = 0.f;
        #pragma unroll
        for (int ky = 0; ky < 7; ++ky) {
            #pragma unroll
            for (int kx = 0; kx < 7; ++kx)
                acc = fmaf(xs[(oy + ky) * 31 + ox + kx], zs[ky * 7 + kx], acc);
        }
        o[p] = acc;
    }
}

// ---------------------------------------------------------------- implicit-GEMM 3x3 conv (pad 1)
// out[m=(b,pix)][n=co] = sum_k in_gathered * w,  K = CIN*9, split in 2 halves (blockIdx.z)
// partials: part + kz*(SEQM*192);  TRANS_OUT=false -> (m,n) layout; true -> (b,co,pix) layout
template<int CIN, int S, int HIN, bool TRANS_OUT>
__global__ __launch_bounds__(256) void conv_gemm(
    const float* __restrict__ in, const float* __restrict__ w,
    float* __restrict__ part)
{
    constexpr int KH = CIN / 2;      // cins per K-half
    constexpr int NT = KH / 4;       // K-tiles (4 cin * 9 = 36 k each)
    __shared__ float smem[2 * 36 * 68];
    float* As = smem;                // [36][68]  k-major, m minor
    float* Ws = smem + 36 * 68;      // [36][68]  k-major, n minor
    const int m0 = blockIdx.x * 64;
    const int n0 = blockIdx.y * 64;
    const int kz = blockIdx.z;
    const int t  = threadIdx.x;
    const int lm = t & 63;           // row within tile (A: m, W: n)
    const int lc = t >> 6;           // 0..3 cin-within-tile
    const int m  = m0 + lm;
    const int b  = m / NPIX;
    const int pix = m % NPIX;
    const int oy = pix / WD, ox = pix % WD;
    const int iy0 = S * oy - 1, ix0 = S * ox - 1;
    bool okY[3], okX[3];
    #pragma unroll
    for (int k = 0; k < 3; ++k) {
        okY[k] = (unsigned)(iy0 + k) < (unsigned)HIN;
        okX[k] = (unsigned)(ix0 + k) < (unsigned)HIN;
    }
    const float* pA = in + ((size_t)b * CIN + kz * KH + lc) * (HIN * HIN) + iy0 * HIN + ix0;
    const float* pW = w + ((size_t)(n0 + lm) * CIN + kz * KH + lc) * 9;
    const int tx = t & 15, ty = t >> 4;
    float acc[4][4] = {};
    float av[9], wv[9];
    #pragma unroll
    for (int ky = 0; ky < 3; ++ky)
        #pragma unroll
        for (int kx = 0; kx < 3; ++kx)
            av[ky * 3 + kx] = (okY[ky] && okX[kx]) ? pA[ky * HIN + kx] : 0.f;
    #pragma unroll
    for (int j = 0; j < 9; ++j) wv[j] = pW[j];

    for (int kt = 0; kt < NT; ++kt) {
        __syncthreads();
        {
            float* a  = As + (lc * 9) * 68 + lm;
            float* wd = Ws + (lc * 9) * 68 + lm;
            #pragma unroll
            for (int j = 0; j < 9; ++j) { a[j * 68] = av[j]; wd[j * 68] = wv[j]; }
        }
        __syncthreads();
        if (kt + 1 < NT) {
            pA += 4 * HIN * HIN;
            pW += 36;
            #pragma unroll
            for (int ky = 0; ky < 3; ++ky)
                #pragma unroll
                for (int kx = 0; kx < 3; ++kx)
                    av[ky * 3 + kx] = (okY[ky] && okX[kx]) ? pA[ky * HIN + kx] : 0.f;
            #pragma unroll
            for (int j = 0; j < 9; ++j) wv[j] = pW[j];
        }
        #pragma unroll
        for (int kk = 0; kk < 36; ++kk) {
            const float4 a4 = *(const float4*)&As[kk * 68 + ty * 4];
            const float4 w4 = *(const float4*)&Ws[kk * 68 + tx * 4];
            const float aa[4] = {a4.x, a4.y, a4.z, a4.w};
            const float wb[4] = {w4.x, w4.y, w4.z, w4.w};
            #pragma unroll
            for (int i = 0; i < 4; ++i)
                #pragma unroll
                for (int j = 0; j < 4; ++j)
                    acc[i][j] = fmaf(aa[i], wb[j], acc[i][j]);
        }
    }
    part += (size_t)kz * ((size_t)SEQM * C192);
    if (!TRANS_OUT) {
        #pragma unroll
        for (int i = 0; i < 4; ++i) {
            int mm = m0 + ty * 4 + i;
            float4 v = make_float4(acc[i][0], acc[i][1], acc[i][2], acc[i][3]);
            *(float4*)&part[(size_t)mm * C192 + n0 + tx * 4] = v;
        }
    } else {
        __syncthreads();                 // done reading As/Ws
        float* Cl = smem;                // [64][65]
        #pragma unroll
        for (int i = 0; i < 4; ++i)
            #pragma unroll
            for (int j = 0; j < 4; ++j)
                Cl[(tx * 4 + j) * 65 + ty * 4 + i] = acc[i][j];
        __syncthreads();
        #pragma unroll
        for (int rep = 0; rep < 16; ++rep) {
            int nl = rep * 4 + lc;
            part[((size_t)b * C192 + n0 + nl) * NPIX + pix] = Cl[nl * 65 + lm];
        }
    }
}

// ---------------------------------------------------------------- reduce 2 partials + BN + ReLU -> (b,pix,c)
__global__ __launch_bounds__(256) void reduce_bn_relu(
    const float* __restrict__ p, const float* __restrict__ g,
    const float* __restrict__ bb, const float* __restrict__ mm,
    const float* __restrict__ vv, float* __restrict__ out)
{
    const int i = blockIdx.x * 256 + threadIdx.x;     // float4 index, total SEQM*48
    const int c4 = i % 48;
    const float4* p4 = (const float4*)p;
    float4 a = p4[i];
    float4 bpart = p4[i + (size_t)SEQM * 48];
    float4 g4 = *(const float4*)&g[c4 * 4];
    float4 b4 = *(const float4*)&bb[c4 * 4];
    float4 m4 = *(const float4*)&mm[c4 * 4];
    float4 v4 = *(const float4*)&vv[c4 * 4];
    float4 r;
    {
        float sc = g4.x * rsqrtf(v4.x + 1e-5f); r.x = fmaxf(fmaf(a.x + bpart.x - m4.x, sc, b4.x), 0.f);
    }
    { float sc = g4.y * rsqrtf(v4.y + 1e-5f); r.y = fmaxf(fmaf(a.y + bpart.y - m4.y, sc, b4.y), 0.f); }
    { float sc = g4.z * rsqrtf(v4.z + 1e-5f); r.z = fmaxf(fmaf(a.z + bpart.z - m4.z, sc, b4.z), 0.f); }
    { float sc = g4.w * rsqrtf(v4.w + 1e-5f); r.w = fmaxf(fmaf(a.w + bpart.w - m4.w, sc, b4.w), 0.f); }
    ((float4*)out)[i] = r;
}

// ---------------------------------------------------------------- reduce 2 partials + conv-bias + GroupNorm(32) + ReLU, (b,c,pix) layout
__global__ __launch_bounds__(256) void gn_reduce_relu(
    const float* __restrict__ p, const float* __restrict__ cbias,
    const float* __restrict__ g, const float* __restrict__ bgn,
    float* __restrict__ out)
{
    const int blk = blockIdx.x;          // b*32 + grp
    const int bb = blk / 32, grp = blk % 32;
    const size_t base = ((size_t)bb * C192 + grp * 6) * NPIX;
    const float* p0 = p + base;
    const float* p1 = p + (size_t)SEQM * C192 + base;
    const int N = 6 * NPIX;              // 1014
    const int t = threadIdx.x;
    float vals[4];
    float s = 0.f, s2 = 0.f;
    #pragma unroll
    for (int i = 0; i < 4; ++i) {
        int idx = t + i * 256;
        float v = 0.f;
        if (idx < N) v = p0[idx] + p1[idx] + cbias[grp * 6 + idx / NPIX];
        vals[i] = v; s += v; s2 += v * v;
    }
    #pragma unroll
    for (int o = 32; o; o >>= 1) { s += __shfl_down(s, o); s2 += __shfl_down(s2, o); }
    __shared__ float redS[4], redS2[4];
    int wid = t >> 6, lane = t & 63;
    if (lane == 0) { redS[wid] = s; redS2[wid] = s2; }
    __syncthreads();
    float S  = redS[0] + redS[1] + redS[2] + redS[3];
    float S2 = redS2[0] + redS2[1] + redS2[2] + redS2[3];
    float mean = S / (float)N;
    float var  = S2 / (float)N - mean * mean;
    float inv  = rsqrtf(var + 1e-5f);
    #pragma unroll
    for (int i = 0; i < 4; ++i) {
        int idx = t + i * 256;
        if (idx < N) {
            int ch = grp * 6 + idx / NPIX;
            float y = (vals[i] - mean) * inv * g[ch] + bgn[ch];
            out[base + idx] = fmaxf(y, 0.f);
        }
    }
}

// ---------------------------------------------------------------- small conv 3x3 s1 p1 + bias (head convs), (b,c,n) in/out
template<int CO_T>
__global__ __launch_bounds__(192) void conv_s1_bias(
    const float* __restrict__ in, const float* __restrict__ w,
    const float* __restrict__ bias, float* __restrict__ out)
{
    const int b    = blockIdx.x;
    const int co0  = blockIdx.y * CO_T;
    const int Cout = gridDim.y * CO_T;
    const int t    = threadIdx.x;
    __shared__ float xs[4 * 225];  // 4 padded 15x15 planes
    float acc[CO_T];
    #pragma unroll
    for (int i = 0; i < CO_T; ++i) acc[i] = 0.f;
    int py = 0, px = 0;
    if (t < NPIX) { py = t / WD; px = t % WD; }
    const float* inb = in + (size_t)b * C192 * NPIX;

    for (int c0 = 0; c0 < C192; c0 += 4) {
        __syncthreads();
        for (int i = t; i < 4 * 225; i += 192) {
            int pl = i / 225, pp = i % 225;
            int y = pp / 15, x = pp % 15;
            float v = 0.f;
            if (y >= 1 && y <= 13 && x >= 1 && x <= 13)
                v = inb[(size_t)(c0 + pl) * NPIX + (y - 1) * WD + (x - 1)];
            xs[i] = v;
        }
        __syncthreads();
        if (t < NPIX) {
            #pragma unroll
            for (int pl = 0; pl < 4; ++pl) {
                float xv[9];
                const float* xp = xs + pl * 225;
                #pragma unroll
                for (int ky = 0; ky < 3; ++ky) {
                    #pragma unroll
                    for (int kx = 0; kx < 3; ++kx)
                        xv[ky * 3 + kx] = xp[(py + ky) * 15 + px + kx];
                }
                #pragma unroll
                for (int co = 0; co < CO_T; ++co) {
                    const float* wc = w + ((size_t)(co0 + co) * C192 + (c0 + pl)) * 9;
                    #pragma unroll
                    for (int k = 0; k < 9; ++k)
                        acc[co] = fmaf(xv[k], wc[k], acc[co]);
                }
            }
        }
    }
    if (t < NPIX) {
        #pragma unroll
        for (int co = 0; co < CO_T; ++co) {
            int c = co0 + co;
            out[((size_t)b * Cout + c) * NPIX + t] = acc[co] + bias[c];
        }
    }
}

// ---------------------------------------------------------------- GEMM: C[M,N] = A[M,K] @ W[N,K]^T + bias (+ReLU)
template<bool RELU>
__global__ __launch_bounds__(256) void gemm_nt(
    const float* __restrict__ A, const float* __restrict__ W,
    const float* __restrict__ bias, float* __restrict__ C,
    int M, int N, int K)
{
    const int BK = 32;
    __shared__ float As[BK][68];
    __shared__ float Ws[BK][68];
    const int mb = blockIdx.x, nb = blockIdx.y;
    const int t = threadIdx.x;
    const int tx = t % 16, ty = t / 16;
    float acc[4][4] = {};
    for (int k0 = 0; k0 < K; k0 += BK) {
        __syncthreads();
        {
            int r = t / 8, kv = (t % 8) * 4;
            const float4 a0 = *(const float4*)&A[(size_t)(mb * 64 + r) * K + k0 + kv];
            const float4 a1 = *(const float4*)&A[(size_t)(mb * 64 + r + 32) * K + k0 + kv];
            As[kv + 0][r] = a0.x; As[kv + 1][r] = a0.y; As[kv + 2][r] = a0.z; As[kv + 3][r] = a0.w;
            As[kv + 0][r + 32] = a1.x; As[kv + 1][r + 32] = a1.y; As[kv + 2][r + 32] = a1.z; As[kv + 3][r + 32] = a1.w;
            const float4 w0 = *(const float4*)&W[(size_t)(nb * 64 + r) * K + k0 + kv];
            const float4 w1 = *(const float4*)&W[(size_t)(nb * 64 + r + 32) * K + k0 + kv];
            Ws[kv + 0][r] = w0.x; Ws[kv + 1][r] = w0.y; Ws[kv + 2][r] = w0.z; Ws[kv + 3][r] = w0.w;
            Ws[kv + 0][r + 32] = w1.x; Ws[kv + 1][r + 32] = w1.y; Ws[kv + 2][r + 32] = w1.z; Ws[kv + 3][r + 32] = w1.w;
        }
        __syncthreads();
        #pragma unroll
        for (int kk = 0; kk < BK; ++kk) {
            const float4 a4 = *(const float4*)&As[kk][ty * 4];
            const float4 w4 = *(const float4*)&Ws[kk][tx * 4];
            const float aa[4] = {a4.x, a4.y, a4.z, a4.w};
            const float wb[4] = {w4.x, w4.y, w4.z, w4.w};
            #pragma unroll
            for (int i = 0; i < 4; ++i)
                #pragma unroll
                for (int j = 0; j < 4; ++j)
                    acc[i][j] = fmaf(aa[i], wb[j], acc[i][j]);
        }
    }
    const float4 bv = *(const float4*)&bias[nb * 64 + tx * 4];
    #pragma unroll
    for (int i = 0; i < 4; ++i) {
        int mrow = mb * 64 + ty * 4 + i;
        float4 v = make_float4(acc[i][0] + bv.x, acc[i][1] + bv.y,
                               acc[i][2] + bv.z, acc[i][3] + bv.w);
        if (RELU) { v.x = fmaxf(v.x, 0.f); v.y = fmaxf(v.y, 0.f); v.z = fmaxf(v.z, 0.f); v.w = fmaxf(v.w, 0.f); }
        *(float4*)&C[(size_t)mrow * N + nb * 64 + tx * 4] = v;
    }
}

// ---------------------------------------------------------------- add positional embedding, (b,pix,c) layout
__global__ __launch_bounds__(256) void addpos_kernel(
    const float* __restrict__ src, const float* __restrict__ row_e,
    const float* __restrict__ col_e, float* __restrict__ dst)
{
    const int total = SEQM * C192;
    int i = blockIdx.x * 256 + threadIdx.x;
    if (i >= total) return;
    int c = i % C192;
    int pix = (i / C192) % NPIX;
    float p = (c < 96) ? col_e[(pix % WD) * 96 + c] : row_e[(pix / WD) * 96 + (c - 96)];
    dst[i] = src[i] + p;
}

// ---------------------------------------------------------------- masked attention, (b,pix,c) layout
__global__ __launch_bounds__(192) void attn_kernel(
    const float* __restrict__ Q, const float* __restrict__ K,
    const float* __restrict__ V, const int* __restrict__ mask_size,
    float* __restrict__ O)
{
    const int bh = blockIdx.x;   // b*8 + h
    const int b = bh / NH, h = bh % NH;
    __shared__ float Ks[NPIX][HD];
    __shared__ float Vs[NPIX][HD];
    const int t = threadIdx.x;
    for (int i = t; i < NPIX * HD; i += 192) {
        int n = i / HD, d = i % HD;
        size_t base = ((size_t)b * NPIX + n) * C192 + h * HD + d;
        Ks[n][d] = K[base];
        Vs[n][d] = V[base];
    }
    __syncthreads();
    if (t < NPIX) {
        float q[HD];
        size_t qbase = ((size_t)b * NPIX + t) * C192 + h * HD;
        #pragma unroll
        for (int d = 0; d < HD; ++d) q[d] = Q[qbase + d];
        const int ms2 = mask_size[0] / 2;
        const int ri = t / WD, ci = t % WD;
        const int r0 = max(ri - ms2, 0), r1 = min(ri + ms2, WD - 1);
        const int c0 = max(ci - ms2, 0), c1 = min(ci + ms2, WD - 1);
        float mx = -1e30f, sum = 0.f;
        float o[HD];
        #pragma unroll
        for (int d = 0; d < HD; ++d) o[d] = 0.f;
        const float scale = 0.20412414523193150f;   // 24^-0.5
        for (int rm = r0; rm <= r1; ++rm) {
            for (int cm = c0; cm <= c1; ++cm) {
                int m = rm * WD + cm;
                float s = 0.f;
                #pragma unroll
                for (int d = 0; d < HD; ++d) s = fmaf(q[d], Ks[m][d], s);
                s *= scale;
                if (s > mx) {
                    float f = expf(mx - s);
                    sum *= f;
                    #pragma unroll
                    for (int d = 0; d < HD; ++d) o[d] *= f;
                    mx = s;
                }
                float p = expf(s - mx);
                sum += p;
                #pragma unroll
                for (int d = 0; d < HD; ++d) o[d] = fmaf(p, Vs[m][d], o[d]);
            }
        }
        float r = 1.f / sum;
        #pragma unroll
        for (int d = 0; d < HD; ++d) O[qbase + d] = o[d] * r;
    }
}

// ---------------------------------------------------------------- fused residual-add + LayerNorm(192), in-place
__global__ __launch_bounds__(256) void add_ln_kernel(
    float* __restrict__ x, const float* __restrict__ a,
    const float* __restrict__ g, const float* __restrict__ b)
{
    const int row = blockIdx.x * 4 + (threadIdx.x >> 6);
    const int lane = threadIdx.x & 63;
    float* xp = x + (size_t)row * C192;
    const float* ap = a + (size_t)row * C192;
    float v[3];
    float s = 0.f, s2 = 0.f;
    #pragma unroll
    for (int i = 0; i < 3; ++i) {
        float t = xp[lane + i * 64] + ap[lane + i * 64];
        v[i] = t; s += t; s2 += t * t;
    }
    #pragma unroll
    for (int o = 32; o; o >>= 1) { s += __shfl_down(s, o); s2 += __shfl_down(s2, o); }
    s = __shfl(s, 0); s2 = __shfl(s2, 0);
    float mean = s * (1.f / 192.f);
    float var  = s2 * (1.f / 192.f) - mean * mean;
    float inv  = rsqrtf(var + 1e-5f);
    #pragma unroll
    for (int i = 0; i < 3; ++i) {
        int c = lane + i * 64;
        xp[c] = (v[i] - mean) * inv * g[c] + b[c];
    }
}

// ---------------------------------------------------------------- (b,pix,c) -> (b,c,pix)
__global__ __launch_bounds__(256) void bpc_to_bcp(
    const float* __restrict__ src, float* __restrict__ dst)
{
    __shared__ float tile[32][33];
    const int b = blockIdx.z;
    const int n0 = blockIdx.x * 32, c0 = blockIdx.y * 32;
    const int tx = threadIdx.x % 32, ty = threadIdx.x / 32;
    #pragma unroll
    for (int i = 0; i < 32; i += 8) {
        int n = n0 + ty + i, c = c0 + tx;
        if (n < NPIX) tile[ty + i][tx] = src[((size_t)b * NPIX + n) * C192 + c];
    }
    __syncthreads();
    #pragma unroll
    for (int i = 0; i < 32; i += 8) {
        int c = c0 + ty + i, n = n0 + tx;
        if (n < NPIX) dst[((size_t)b * C192 + c) * NPIX + n] = tile[tx][ty + i];
    }
}

// ---------------------------------------------------------------- launch
extern "C" void kernel_launch(void* const* d_in, const int* in_sizes, int n_in,
                              void* d_out, int out_size, void* d_ws, size_t ws_size,
                              hipStream_t stream)
{
    const float* x0 = (const float*)d_in[0];
    const float* x1 = (const float*)d_in[1];
    const float* x2 = (const float*)d_in[2];
    const float* z0 = (const float*)d_in[3];
    const float* z1 = (const float*)d_in[4];
    const float* z2 = (const float*)d_in[5];
    const float* conv1_w = (const float*)d_in[6];
    const float* conv3_w = (const float*)d_in[7];
    const float* conv2_w = (const float*)d_in[8];
    const float* bn1_g = (const float*)d_in[9];
    const float* bn1_b = (const float*)d_in[10];
    const float* bn1_m = (const float*)d_in[11];
    const float* bn1_v = (const float*)d_in[12];
    const float* bn2_g = (const float*)d_in[13];
    const float* bn2_b = (const float*)d_in[14];
    const float* bn2_m = (const float*)d_in[15];
    const float* bn2_v = (const float*)d_in[16];
    const float* bn3_g = (const float*)d_in[17];
    const float* bn3_b = (const float*)d_in[18];
    const float* bn3_m = (const float*)d_in[19];
    const float* bn3_v = (const float*)d_in[20];
    const float* row_embed = (const float*)d_in[21];
    const float* col_embed = (const float*)d_in[22];
    const float* t_wq = (const float*)d_in[23];
    const float* t_bq = (const float*)d_in[24];
    const float* t_wk = (const float*)d_in[25];
    const float* t_bk = (const float*)d_in[26];
    const float* t_wv = (const float*)d_in[27];
    const float* t_bv = (const float*)d_in[28];
    const float* t_wo = (const float*)d_in[29];
    const float* t_bo = (const float*)d_in[30];
    const float* t_ln1_g = (const float*)d_in[31];
    const float* t_ln1_b = (const float*)d_in[32];
    const float* t_ln2_g = (const float*)d_in[33];
    const float* t_ln2_b = (const float*)d_in[34];
    const float* t_ff1_w = (const float*)d_in[35];
    const float* t_ff1_b = (const float*)d_in[36];
    const float* t_ff2_w = (const float*)d_in[37];
    const float* t_ff2_b = (const float*)d_in[38];
    const float* convloc_w = (const float*)d_in[39];
    const float* convloc_b = (const float*)d_in[40];
    const float* convloc_gn_g = (const float*)d_in[41];
    const float* convloc_gn_b = (const float*)d_in[42];
    const float* loc_out_w = (const float*)d_in[43];
    const float* loc_out_b = (const float*)d_in[44];
    const float* convcls_w = (const float*)d_in[45];
    const float* convcls_b = (const float*)d_in[46];
    const float* convcls_gn_g = (const float*)d_in[47];
    const float* convcls_gn_b = (const float*)d_in[48];
    const float* cls1_w = (const float*)d_in[49];
    const float* cls1_b = (const float*)d_in[50];
    const float* cls2_w = (const float*)d_in[51];
    const float* cls2_b = (const float*)d_in[52];
    const int*   mask_size = (const int*)d_in[53];
    float* out = (float*)d_out;

    // workspace layout (floats) — same footprint as round-1 (known to fit)
    const size_t SZ_X = (size_t)NB * 384 * 625;   // 15,360,000
    const size_t SZ_S = (size_t)SEQM * C192;      // 2,076,672
    float* ws   = (float*)d_ws;
    float* Abuf = ws;
    float* res1 = Abuf + SZ_X;
    float* res2 = res1 + SZ_S;
    float* outb = res2 + SZ_S;
    float* qb   = outb + SZ_S;
    float* kb   = qb + SZ_S;
    float* vb   = kb + SZ_S;
    float* ob   = vb + SZ_S;
    float* resT = ob + SZ_S;
    float* y0   = resT + SZ_S;
    float* y1   = y0 + SZ_S;
    float* pbuf = qb;      // 2 partial buffers = qb+kb region (free during stage A and towers)

    const dim3 cgrid(NPIX, 3, 2);          // implicit-GEMM conv grid (M-tiles, N-tiles, K-halves)
    const int  rgrid = SEQM * 48 / 256;    // reduce_bn_relu
    const dim3 tgrid(6, 6, NB);

    // ---------------- stage A: xcorr -> conv s2 -> BN -> ReLU  => (b,pix,c)
    xcorr_kernel<<<NB * 384, 256, 0, stream>>>(x0, z0, Abuf);
    conv_gemm<384, 2, 25, false><<<cgrid, 256, 0, stream>>>(Abuf, conv1_w, pbuf);
    reduce_bn_relu<<<rgrid, 256, 0, stream>>>(pbuf, bn1_g, bn1_b, bn1_m, bn1_v, res1);

    xcorr_kernel<<<NB * 384, 256, 0, stream>>>(x1, z1, Abuf);
    conv_gemm<384, 2, 25, false><<<cgrid, 256, 0, stream>>>(Abuf, conv3_w, pbuf);
    reduce_bn_relu<<<rgrid, 256, 0, stream>>>(pbuf, bn3_g, bn3_b, bn3_m, bn3_v, res2);

    xcorr_kernel<<<NB * 256, 256, 0, stream>>>(x2, z2, Abuf);
    conv_gemm<256, 2, 25, false><<<cgrid, 256, 0, stream>>>(Abuf, conv2_w, pbuf);
    reduce_bn_relu<<<rgrid, 256, 0, stream>>>(pbuf, bn2_g, bn2_b, bn2_m, bn2_v, outb);

    // ---------------- transformer (2 cross-attention layers), (b,pix,c) order
    const int addpos_grid = (SEQM * C192 + 255) / 256;
    for (int li = 0; li < 2; ++li) {
        const float* mem = (li == 0) ? res1 : res2;
        const float* wq = t_wq + (size_t)li * C192 * C192;
        const float* wk = t_wk + (size_t)li * C192 * C192;
        const float* wv = t_wv + (size_t)li * C192 * C192;
        const float* wo = t_wo + (size_t)li * C192 * C192;
        const float* bq = t_bq + (size_t)li * C192;
        const float* bk = t_bk + (size_t)li * C192;
        const float* bv = t_bv + (size_t)li * C192;
        const float* bo = t_bo + (size_t)li * C192;

        addpos_kernel<<<addpos_grid, 256, 0, stream>>>(outb, row_embed, col_embed, qb);
        addpos_kernel<<<addpos_grid, 256, 0, stream>>>(mem,  row_embed, col_embed, kb);

        gemm_nt<false><<<dim3(SEQM / 64, 3), 256, 0, stream>>>(qb,  wq, bq, vb, SEQM, C192, C192); // Qh
        gemm_nt<false><<<dim3(SEQM / 64, 3), 256, 0, stream>>>(kb,  wk, bk, qb, SEQM, C192, C192); // Kh
        gemm_nt<false><<<dim3(SEQM / 64, 3), 256, 0, stream>>>(mem, wv, bv, kb, SEQM, C192, C192); // Vh

        attn_kernel<<<NB * NH, 192, 0, stream>>>(vb, qb, kb, mask_size, ob);

        gemm_nt<false><<<dim3(SEQM / 64, 3), 256, 0, stream>>>(ob, wo, bo, qb, SEQM, C192, C192);
        add_ln_kernel<<<SEQM / 4, 256, 0, stream>>>(outb, qb,
            t_ln1_g + (size_t)li * C192, t_ln1_b + (size_t)li * C192);

        gemm_nt<true><<<dim3(SEQM / 64, 12), 256, 0, stream>>>(outb,
            t_ff1_w + (size_t)li * 768 * C192, t_ff1_b + (size_t)li * 768, Abuf, SEQM, 768, C192);
        gemm_nt<false><<<dim3(SEQM / 64, 3), 256, 0, stream>>>(Abuf,
            t_ff2_w + (size_t)li * C192 * 768, t_ff2_b + (size_t)li * C192, qb, SEQM, C192, 768);
        add_ln_kernel<<<SEQM / 4, 256, 0, stream>>>(outb, qb,
            t_ln2_g + (size_t)li * C192, t_ln2_b + (size_t)li * C192);
    }

    // ---------------- (b,pix,c) -> (b,c,pix) for the conv towers
    bpc_to_bcp<<<tgrid, 256, 0, stream>>>(outb, resT);

    // ---------------- loc tower (implicit-GEMM conv + fused bias+GN+ReLU)
    {
        const float* yin = resT;
        float* ybufs[2] = { y0, y1 };
        for (int i = 0; i < 3; ++i) {
            conv_gemm<192, 1, 13, true><<<cgrid, 256, 0, stream>>>(yin,
                convloc_w + (size_t)i * C192 * C192 * 9, pbuf);
            gn_reduce_relu<<<NB * 32, 256, 0, stream>>>(pbuf, convloc_b + (size_t)i * C192,
                convloc_gn_g + (size_t)i * C192, convloc_gn_b + (size_t)i * C192, ybufs[i & 1]);
            yin = ybufs[i & 1];
        }
        conv_s1_bias<4><<<dim3(NB, 1), 192, 0, stream>>>(yin, loc_out_w, loc_out_b, out);
    }

    // ---------------- cls tower
    {
        const float* yin = resT;
        float* ybufs[2] = { y1, y0 };
        for (int i = 0; i < 3; ++i) {
            conv_gemm<192, 1, 13, true><<<cgrid, 256, 0, stream>>>(yin,
                convcls_w + (size_t)i * C192 * C192 * 9, pbuf);
            gn_reduce_relu<<<NB * 32, 256, 0, stream>>>(pbuf, convcls_b + (size_t)i * C192,
                convcls_gn_g + (size_t)i * C192, convcls_gn_b + (size_t)i * C192, ybufs[i & 1]);
            yin = ybufs[i & 1];
        }
        conv_s1_bias<2><<<dim3(NB, 1), 192, 0, stream>>>(yin, cls1_w, cls1_b, out + (size_t)NB * 4 * NPIX);
        conv_s1_bias<1><<<dim3(NB, 1), 192, 0, stream>>>(yin, cls2_w, cls2_b, out + (size_t)NB * 6 * NPIX);
    }
}

// Round 3
// 2282.446 us; speedup vs baseline: 3.5401x; 1.0993x over previous
//
#include <hip/hip_runtime.h>
#include <cstdint>
#include <cstddef>

// ---------------------------------------------------------------- constants
#define NB   64      // batch
#define C192 192
#define NPIX 169     // 13*13
#define WD   13
#define NH   8
#define HD   24      // head dim
#define SEQM (NPIX*NB)   // 10816 rows, ordering m = b*169 + pix

typedef __attribute__((ext_vector_type(8))) short  s16x8;   // 8 bf16 (4 VGPRs)
typedef __attribute__((ext_vector_type(4))) float  f32x4;

// RNE fp32 -> bf16 split: x ~= hi + lo (each bf16)
__device__ __forceinline__ void split2(float x, unsigned short& h, unsigned short& l) {
    unsigned int u = __float_as_uint(x);
    unsigned int r = u + 0x7fffu + ((u >> 16) & 1u);
    h = (unsigned short)(r >> 16);
    float hf = __uint_as_float((unsigned int)h << 16);
    float res = x - hf;
    unsigned int u2 = __float_as_uint(res);
    unsigned int r2 = u2 + 0x7fffu + ((u2 >> 16) & 1u);
    l = (unsigned short)(r2 >> 16);
}

// ---------------------------------------------------------------- weight pre-split kernels
// GEMM weight [N][K] -> chunk-blocked bf16 hi/lo: dst[((ck*N)+n)*32 + kg*8 + j]
__global__ __launch_bounds__(256) void split_gemm_w(
    const float* __restrict__ w, unsigned short* __restrict__ hi,
    unsigned short* __restrict__ lo, int N, int K)
{
    int tid = blockIdx.x * 256 + threadIdx.x;         // N*K/8 threads exactly
    int K8 = K >> 3;
    int n = tid / K8, kg8 = tid % K8;
    int ck = kg8 >> 2, kgl = kg8 & 3;
    const float* src = w + (size_t)n * K + kg8 * 8;
    size_t dst = ((size_t)ck * N + n) * 32 + kgl * 8;
    s16x8 h8, l8;
    #pragma unroll
    for (int j = 0; j < 8; ++j) {
        unsigned short h, l; split2(src[j], h, l);
        h8[j] = (short)h; l8[j] = (short)l;
    }
    *(s16x8*)(hi + dst) = h8;
    *(s16x8*)(lo + dst) = l8;
}

// conv weight [CO][CIN][9] -> per kz-half, kidx-major chunk-blocked bf16 hi/lo
template<int CIN, int CO>
__global__ __launch_bounds__(256) void split_conv_w(
    const float* __restrict__ w, unsigned short* __restrict__ hi,
    unsigned short* __restrict__ lo)
{
    constexpr int CINh = CIN / 2;
    constexpr int Klocal = 9 * CINh;
    constexpr int K8 = Klocal / 8;
    constexpr int NCH = Klocal / 32;
    constexpr int CPK = CINh / 32;
    int tid = blockIdx.x * 256 + threadIdx.x;         // 2*CO*K8 threads exactly
    int kz = tid / (CO * K8);
    int rem = tid % (CO * K8);
    int n = rem / K8, kg8 = rem % K8;
    int ck = kg8 >> 2, kgl = kg8 & 3;
    int kidx = ck / CPK;
    int cin0 = (ck % CPK) * 32 + kgl * 8;
    s16x8 h8, l8;
    #pragma unroll
    for (int j = 0; j < 8; ++j) {
        float v = w[((size_t)n * CIN + kz * CINh + cin0 + j) * 9 + kidx];
        unsigned short h, l; split2(v, h, l);
        h8[j] = (short)h; l8[j] = (short)l;
    }
    size_t dst = ((size_t)(kz * NCH + ck) * CO + n) * 32 + kgl * 8;
    *(s16x8*)(hi + dst) = h8;
    *(s16x8*)(lo + dst) = l8;
}

// ---------------------------------------------------------------- xcorr
__global__ __launch_bounds__(256) void xcorr_kernel(
    const float* __restrict__ x, const float* __restrict__ z,
    float* __restrict__ out)
{
    int bc = blockIdx.x;
    const float* xin = x + (size_t)bc * 961;
    const float* zin = z + (size_t)bc * 49;
    float* o = out + (size_t)bc * 625;
    __shared__ float xs[961];
    __shared__ float zs[49];
    for (int i = threadIdx.x; i < 961; i += 256) xs[i] = xin[i];
    if (threadIdx.x < 49) zs[threadIdx.x] = zin[threadIdx.x];
    __syncthreads();
    for (int p = threadIdx.x; p < 625; p += 256) {
        int oy = p / 25, ox = p % 25;
        float acc = 0.f;
        #pragma unroll
        for (int ky = 0; ky < 7; ++ky) {
            #pragma unroll
            for (int kx = 0; kx < 7; ++kx)
                acc = fmaf(xs[(oy + ky) * 31 + ox + kx], zs[ky * 7 + kx], acc);
        }
        o[p] = acc;
    }
}

// ---------------------------------------------------------------- MFMA implicit-GEMM 3x3 conv (pad 1), split-bf16
// K-order (per kz half): k = kidx*CINh + cin.  part + kz*(SEQM*192).
template<int CIN, int S, int HIN, bool TRANS_OUT>
__global__ __launch_bounds__(256) void conv_mfma(
    const float* __restrict__ in, const unsigned short* __restrict__ whi,
    const unsigned short* __restrict__ wlo, int nstride, int noff,
    float* __restrict__ part)
{
    constexpr int CINh = CIN / 2;
    constexpr int NCH  = (9 * CINh) / 32;
    constexpr int CPK  = CINh / 32;
    constexpr int HIN2 = HIN * HIN;
    __shared__ float smemf[4224];                  // 16.9 KB: staging (16KB) U Cl(64x65)
    unsigned short* Ahi = (unsigned short*)smemf;  // [2048]
    unsigned short* Alo = Ahi + 2048;

    const int t = threadIdx.x;
    const int l = t & 63, wave = t >> 6;
    const int mh = wave & 1, nh = wave >> 1;
    const int lm16 = l & 15, kgl = l >> 4;
    const int m0 = blockIdx.x * 64, n0 = blockIdx.y * 64, kz = blockIdx.z;

    // ---- staging ids (thread -> (m row, k-group))
    const int sm = t >> 2, skg = t & 3;
    const int ms = m0 + sm;
    const int bs = ms / NPIX, pixs = ms % NPIX;
    const int oy = pixs / WD, ox = pixs % WD;
    const int iy0 = S * oy - 1, ix0 = S * ox - 1;
    bool okY[3], okX[3];
    #pragma unroll
    for (int k = 0; k < 3; ++k) {
        okY[k] = (unsigned)(iy0 + k) < (unsigned)HIN;
        okX[k] = (unsigned)(ix0 + k) < (unsigned)HIN;
    }
    const float* inb = in + ((size_t)bs * CIN + kz * CINh) * HIN2;
    const int swz = sm * 32 + ((skg ^ ((sm >> 1) & 3)) * 8);

    // ---- fragment read offsets (chunk-invariant)
    int ard[2];
    #pragma unroll
    for (int i = 0; i < 2; ++i) {
        int m = mh * 32 + i * 16 + lm16;
        ard[i] = m * 32 + ((kgl ^ ((m >> 1) & 3)) * 8);
    }
    size_t wof[2];
    #pragma unroll
    for (int jf = 0; jf < 2; ++jf) {
        int n = noff + n0 + nh * 32 + jf * 16 + lm16;
        wof[jf] = (size_t)n * 32 + kgl * 8;
    }
    const size_t kzbase = (size_t)kz * NCH;

    f32x4 acc[2][2];
    #pragma unroll
    for (int i = 0; i < 2; ++i)
        #pragma unroll
        for (int j = 0; j < 2; ++j)
            acc[i][j] = (f32x4){0.f, 0.f, 0.f, 0.f};

    for (int ck = 0; ck < NCH; ++ck) {
        const int kidx = ck / CPK;
        const int cin0 = (ck % CPK) * 32;
        const int ky = kidx / 3, kx = kidx % 3;
        // W fragments: direct global (L2-hot, coalesced)
        const unsigned short* wb  = whi + (kzbase + ck) * (size_t)nstride * 32;
        const unsigned short* wbl = wlo + (kzbase + ck) * (size_t)nstride * 32;
        s16x8 wh[2], wl[2];
        #pragma unroll
        for (int jf = 0; jf < 2; ++jf) {
            wh[jf] = *(const s16x8*)(wb + wof[jf]);
            wl[jf] = *(const s16x8*)(wbl + wof[jf]);
        }
        // A gather + split
        const bool ok = okY[ky] && okX[kx];
        const float* src = inb + (size_t)(cin0 + skg * 8) * HIN2 + (iy0 + ky) * HIN + (ix0 + kx);
        float av[8];
        #pragma unroll
        for (int j = 0; j < 8; ++j) av[j] = ok ? src[(size_t)j * HIN2] : 0.f;
        s16x8 h8, l8;
        #pragma unroll
        for (int j = 0; j < 8; ++j) {
            unsigned short h, lw; split2(av[j], h, lw);
            h8[j] = (short)h; l8[j] = (short)lw;
        }
        __syncthreads();
        *(s16x8*)(Ahi + swz) = h8;
        *(s16x8*)(Alo + swz) = l8;
        __syncthreads();
        s16x8 ah[2], al[2];
        #pragma unroll
        for (int i = 0; i < 2; ++i) {
            ah[i] = *(const s16x8*)(Ahi + ard[i]);
            al[i] = *(const s16x8*)(Alo + ard[i]);
        }
        #pragma unroll
        for (int i = 0; i < 2; ++i)
            #pragma unroll
            for (int jf = 0; jf < 2; ++jf) {
                acc[i][jf] = __builtin_amdgcn_mfma_f32_16x16x32_bf16(ah[i], wl[jf], acc[i][jf], 0, 0, 0);
                acc[i][jf] = __builtin_amdgcn_mfma_f32_16x16x32_bf16(al[i], wh[jf], acc[i][jf], 0, 0, 0);
                acc[i][jf] = __builtin_amdgcn_mfma_f32_16x16x32_bf16(ah[i], wh[jf], acc[i][jf], 0, 0, 0);
            }
    }

    part += (size_t)kz * ((size_t)SEQM * C192);
    if (!TRANS_OUT) {
        #pragma unroll
        for (int i = 0; i < 2; ++i)
            #pragma unroll
            for (int jf = 0; jf < 2; ++jf)
                #pragma unroll
                for (int r = 0; r < 4; ++r) {
                    int m = m0 + mh * 32 + i * 16 + kgl * 4 + r;
                    int n = n0 + nh * 32 + jf * 16 + lm16;
                    part[(size_t)m * C192 + n] = acc[i][jf][r];
                }
    } else {
        __syncthreads();
        float* Cl = smemf;                       // [64][65]
        #pragma unroll
        for (int i = 0; i < 2; ++i)
            #pragma unroll
            for (int jf = 0; jf < 2; ++jf)
                #pragma unroll
                for (int r = 0; r < 4; ++r) {
                    int ml = mh * 32 + i * 16 + kgl * 4 + r;
                    int nl = nh * 32 + jf * 16 + lm16;
                    Cl[nl * 65 + ml] = acc[i][jf][r];
                }
        __syncthreads();
        const int m_l = t & 63;
        const int mm = m0 + m_l;
        const int b2 = mm / NPIX, px2 = mm % NPIX;
        #pragma unroll
        for (int rep = 0; rep < 16; ++rep) {
            int nl = rep * 4 + (t >> 6);
            part[((size_t)b2 * C192 + n0 + nl) * NPIX + px2] = Cl[nl * 65 + m_l];
        }
    }
}

// ---------------------------------------------------------------- MFMA GEMM, split-bf16: C[M,N] = A[M,K] @ W[N,K]^T + bias (+ReLU)
template<bool RELU>
__global__ __launch_bounds__(256) void gemm_mfma(
    const float* __restrict__ A, const unsigned short* __restrict__ whi,
    const unsigned short* __restrict__ wlo, const float* __restrict__ bias,
    float* __restrict__ C, int N, int K, int nstride, int noff)
{
    __shared__ unsigned short smem[4096];
    unsigned short* Ahi = smem;
    unsigned short* Alo = smem + 2048;
    const int t = threadIdx.x;
    const int l = t & 63, wave = t >> 6;
    const int mh = wave & 1, nh = wave >> 1;
    const int lm16 = l & 15, kgl = l >> 4;
    const int m0 = blockIdx.x * 64, n0 = blockIdx.y * 64;
    const int NCH = K >> 5;

    const int sm = t >> 2, skg = t & 3;
    const float* arow = A + (size_t)(m0 + sm) * K + skg * 8;
    const int swz = sm * 32 + ((skg ^ ((sm >> 1) & 3)) * 8);

    int ard[2];
    #pragma unroll
    for (int i = 0; i < 2; ++i) {
        int m = mh * 32 + i * 16 + lm16;
        ard[i] = m * 32 + ((kgl ^ ((m >> 1) & 3)) * 8);
    }
    size_t wof[2];
    #pragma unroll
    for (int jf = 0; jf < 2; ++jf) {
        int n = noff + n0 + nh * 32 + jf * 16 + lm16;
        wof[jf] = (size_t)n * 32 + kgl * 8;
    }

    f32x4 acc[2][2];
    #pragma unroll
    for (int i = 0; i < 2; ++i)
        #pragma unroll
        for (int j = 0; j < 2; ++j)
            acc[i][j] = (f32x4){0.f, 0.f, 0.f, 0.f};

    for (int ck = 0; ck < NCH; ++ck) {
        const unsigned short* wb  = whi + (size_t)ck * nstride * 32;
        const unsigned short* wbl = wlo + (size_t)ck * nstride * 32;
        s16x8 wh[2], wl[2];
        #pragma unroll
        for (int jf = 0; jf < 2; ++jf) {
            wh[jf] = *(const s16x8*)(wb + wof[jf]);
            wl[jf] = *(const s16x8*)(wbl + wof[jf]);
        }
        float av[8];
        {
            const float4 a0 = *(const float4*)(arow + ck * 32);
            const float4 a1 = *(const float4*)(arow + ck * 32 + 4);
            av[0] = a0.x; av[1] = a0.y; av[2] = a0.z; av[3] = a0.w;
            av[4] = a1.x; av[5] = a1.y; av[6] = a1.z; av[7] = a1.w;
        }
        s16x8 h8, l8;
        #pragma unroll
        for (int j = 0; j < 8; ++j) {
            unsigned short h, lw; split2(av[j], h, lw);
            h8[j] = (short)h; l8[j] = (short)lw;
        }
        __syncthreads();
        *(s16x8*)(Ahi + swz) = h8;
        *(s16x8*)(Alo + swz) = l8;
        __syncthreads();
        s16x8 ah[2], al[2];
        #pragma unroll
        for (int i = 0; i < 2; ++i) {
            ah[i] = *(const s16x8*)(Ahi + ard[i]);
            al[i] = *(const s16x8*)(Alo + ard[i]);
        }
        #pragma unroll
        for (int i = 0; i < 2; ++i)
            #pragma unroll
            for (int jf = 0; jf < 2; ++jf) {
                acc[i][jf] = __builtin_amdgcn_mfma_f32_16x16x32_bf16(ah[i], wl[jf], acc[i][jf], 0, 0, 0);
                acc[i][jf] = __builtin_amdgcn_mfma_f32_16x16x32_bf16(al[i], wh[jf], acc[i][jf], 0, 0, 0);
                acc[i][jf] = __builtin_amdgcn_mfma_f32_16x16x32_bf16(ah[i], wh[jf], acc[i][jf], 0, 0, 0);
            }
    }

    #pragma unroll
    for (int jf = 0; jf < 2; ++jf) {
        int n = n0 + nh * 32 + jf * 16 + lm16;
        float bv = bias[n];
        #pragma unroll
        for (int i = 0; i < 2; ++i)
            #pragma unroll
            for (int r = 0; r < 4; ++r) {
                int m = m0 + mh * 32 + i * 16 + kgl * 4 + r;
                float v = acc[i][jf][r] + bv;
                if (RELU) v = fmaxf(v, 0.f);
                C[(size_t)m * N + n] = v;
            }
    }
}

// ---------------------------------------------------------------- reduce 2 partials + BN + ReLU -> (b,pix,c)
__global__ __launch_bounds__(256) void reduce_bn_relu(
    const float* __restrict__ p, const float* __restrict__ g,
    const float* __restrict__ bb, const float* __restrict__ mm,
    const float* __restrict__ vv, float* __restrict__ out)
{
    const int i = blockIdx.x * 256 + threadIdx.x;     // float4 index, total SEQM*48
    const int c4 = i % 48;
    const float4* p4 = (const float4*)p;
    float4 a = p4[i];
    float4 bpart = p4[i + (size_t)SEQM * 48];
    float4 g4 = *(const float4*)&g[c4 * 4];
    float4 b4 = *(const float4*)&bb[c4 * 4];
    float4 m4 = *(const float4*)&mm[c4 * 4];
    float4 v4 = *(const float4*)&vv[c4 * 4];
    float4 r;
    { float sc = g4.x * rsqrtf(v4.x + 1e-5f); r.x = fmaxf(fmaf(a.x + bpart.x - m4.x, sc, b4.x), 0.f); }
    { float sc = g4.y * rsqrtf(v4.y + 1e-5f); r.y = fmaxf(fmaf(a.y + bpart.y - m4.y, sc, b4.y), 0.f); }
    { float sc = g4.z * rsqrtf(v4.z + 1e-5f); r.z = fmaxf(fmaf(a.z + bpart.z - m4.z, sc, b4.z), 0.f); }
    { float sc = g4.w * rsqrtf(v4.w + 1e-5f); r.w = fmaxf(fmaf(a.w + bpart.w - m4.w, sc, b4.w), 0.f); }
    ((float4*)out)[i] = r;
}

// ---------------------------------------------------------------- reduce 2 partials + conv-bias + GroupNorm(32) + ReLU, (b,c,pix)
__global__ __launch_bounds__(256) void gn_reduce_relu(
    const float* __restrict__ p, const float* __restrict__ cbias,
    const float* __restrict__ g, const float* __restrict__ bgn,
    float* __restrict__ out)
{
    const int blk = blockIdx.x;          // b*32 + grp
    const int bb = blk / 32, grp = blk % 32;
    const size_t base = ((size_t)bb * C192 + grp * 6) * NPIX;
    const float* p0 = p + base;
    const float* p1 = p + (size_t)SEQM * C192 + base;
    const int N = 6 * NPIX;              // 1014
    const int t = threadIdx.x;
    float vals[4];
    float s = 0.f, s2 = 0.f;
    #pragma unroll
    for (int i = 0; i < 4; ++i) {
        int idx = t + i * 256;
        float v = 0.f;
        if (idx < N) v = p0[idx] + p1[idx] + cbias[grp * 6 + idx / NPIX];
        vals[i] = v; s += v; s2 += v * v;
    }
    #pragma unroll
    for (int o = 32; o; o >>= 1) { s += __shfl_down(s, o); s2 += __shfl_down(s2, o); }
    __shared__ float redS[4], redS2[4];
    int wid = t >> 6, lane = t & 63;
    if (lane == 0) { redS[wid] = s; redS2[wid] = s2; }
    __syncthreads();
    float S  = redS[0] + redS[1] + redS[2] + redS[3];
    float S2 = redS2[0] + redS2[1] + redS2[2] + redS2[3];
    float mean = S / (float)N;
    float var  = S2 / (float)N - mean * mean;
    float inv  = rsqrtf(var + 1e-5f);
    #pragma unroll
    for (int i = 0; i < 4; ++i) {
        int idx = t + i * 256;
        if (idx < N) {
            int ch = grp * 6 + idx / NPIX;
            float y = (vals[i] - mean) * inv * g[ch] + bgn[ch];
            out[base + idx] = fmaxf(y, 0.f);
        }
    }
}

// ---------------------------------------------------------------- small head conv 3x3 s1 p1 + bias, (b,c,n) in/out
template<int CO_T>
__global__ __launch_bounds__(192) void conv_s1_bias(
    const float* __restrict__ in, const float* __restrict__ w,
    const float* __restrict__ bias, float* __restrict__ out)
{
    const int b    = blockIdx.x;
    const int co0  = blockIdx.y * CO_T;
    const int Cout = gridDim.y * CO_T;
    const int t    = threadIdx.x;
    __shared__ float xs[4 * 225];
    float acc[CO_T];
    #pragma unroll
    for (int i = 0; i < CO_T; ++i) acc[i] = 0.f;
    int py = 0, px = 0;
    if (t < NPIX) { py = t / WD; px = t % WD; }
    const float* inb = in + (size_t)b * C192 * NPIX;

    for (int c0 = 0; c0 < C192; c0 += 4) {
        __syncthreads();
        for (int i = t; i < 4 * 225; i += 192) {
            int pl = i / 225, pp = i % 225;
            int y = pp / 15, x = pp % 15;
            float v = 0.f;
            if (y >= 1 && y <= 13 && x >= 1 && x <= 13)
                v = inb[(size_t)(c0 + pl) * NPIX + (y - 1) * WD + (x - 1)];
            xs[i] = v;
        }
        __syncthreads();
        if (t < NPIX) {
            #pragma unroll
            for (int pl = 0; pl < 4; ++pl) {
                float xv[9];
                const float* xp = xs + pl * 225;
                #pragma unroll
                for (int ky = 0; ky < 3; ++ky) {
                    #pragma unroll
                    for (int kx = 0; kx < 3; ++kx)
                        xv[ky * 3 + kx] = xp[(py + ky) * 15 + px + kx];
                }
                #pragma unroll
                for (int co = 0; co < CO_T; ++co) {
                    const float* wc = w + ((size_t)(co0 + co) * C192 + (c0 + pl)) * 9;
                    #pragma unroll
                    for (int k = 0; k < 9; ++k)
                        acc[co] = fmaf(xv[k], wc[k], acc[co]);
                }
            }
        }
    }
    if (t < NPIX) {
        #pragma unroll
        for (int co = 0; co < CO_T; ++co) {
            int c = co0 + co;
            out[((size_t)b * Cout + c) * NPIX + t] = acc[co] + bias[c];
        }
    }
}

// ---------------------------------------------------------------- add positional embedding, (b,pix,c)
__global__ __launch_bounds__(256) void addpos_kernel(
    const float* __restrict__ src, const float* __restrict__ row_e,
    const float* __restrict__ col_e, float* __restrict__ dst)
{
    const int total = SEQM * C192;
    int i = blockIdx.x * 256 + threadIdx.x;
    if (i >= total) return;
    int c = i % C192;
    int pix = (i / C192) % NPIX;
    float p = (c < 96) ? col_e[(pix % WD) * 96 + c] : row_e[(pix / WD) * 96 + (c - 96)];
    dst[i] = src[i] + p;
}

// ---------------------------------------------------------------- masked attention, (b,pix,c)
__global__ __launch_bounds__(192) void attn_kernel(
    const float* __restrict__ Q, const float* __restrict__ K,
    const float* __restrict__ V, const int* __restrict__ mask_size,
    float* __restrict__ O)
{
    const int bh = blockIdx.x;   // b*8 + h
    const int b = bh / NH, h = bh % NH;
    __shared__ float Ks[NPIX][HD];
    __shared__ float Vs[NPIX][HD];
    const int t = threadIdx.x;
    for (int i = t; i < NPIX * HD; i += 192) {
        int n = i / HD, d = i % HD;
        size_t base = ((size_t)b * NPIX + n) * C192 + h * HD + d;
        Ks[n][d] = K[base];
        Vs[n][d] = V[base];
    }
    __syncthreads();
    if (t < NPIX) {
        float q[HD];
        size_t qbase = ((size_t)b * NPIX + t) * C192 + h * HD;
        #pragma unroll
        for (int d = 0; d < HD; ++d) q[d] = Q[qbase + d];
        const int ms2 = mask_size[0] / 2;
        const int ri = t / WD, ci = t % WD;
        const int r0 = max(ri - ms2, 0), r1 = min(ri + ms2, WD - 1);
        const int c0 = max(ci - ms2, 0), c1 = min(ci + ms2, WD - 1);
        float mx = -1e30f, sum = 0.f;
        float o[HD];
        #pragma unroll
        for (int d = 0; d < HD; ++d) o[d] = 0.f;
        const float scale = 0.20412414523193150f;   // 24^-0.5
        for (int rm = r0; rm <= r1; ++rm) {
            for (int cm = c0; cm <= c1; ++cm) {
                int m = rm * WD + cm;
                float s = 0.f;
                #pragma unroll
                for (int d = 0; d < HD; ++d) s = fmaf(q[d], Ks[m][d], s);
                s *= scale;
                if (s > mx) {
                    float f = expf(mx - s);
                    sum *= f;
                    #pragma unroll
                    for (int d = 0; d < HD; ++d) o[d] *= f;
                    mx = s;
                }
                float p = expf(s - mx);
                sum += p;
                #pragma unroll
                for (int d = 0; d < HD; ++d) o[d] = fmaf(p, Vs[m][d], o[d]);
            }
        }
        float r = 1.f / sum;
        #pragma unroll
        for (int d = 0; d < HD; ++d) O[qbase + d] = o[d] * r;
    }
}

// ---------------------------------------------------------------- fused residual-add + LayerNorm(192), in-place
__global__ __launch_bounds__(256) void add_ln_kernel(
    float* __restrict__ x, const float* __restrict__ a,
    const float* __restrict__ g, const float* __restrict__ b)
{
    const int row = blockIdx.x * 4 + (threadIdx.x >> 6);
    const int lane = threadIdx.x & 63;
    float* xp = x + (size_t)row * C192;
    const float* ap = a + (size_t)row * C192;
    float v[3];
    float s = 0.f, s2 = 0.f;
    #pragma unroll
    for (int i = 0; i < 3; ++i) {
        float t = xp[lane + i * 64] + ap[lane + i * 64];
        v[i] = t; s += t; s2 += t * t;
    }
    #pragma unroll
    for (int o = 32; o; o >>= 1) { s += __shfl_down(s, o); s2 += __shfl_down(s2, o); }
    s = __shfl(s, 0); s2 = __shfl(s2, 0);
    float mean = s * (1.f / 192.f);
    float var  = s2 * (1.f / 192.f) - mean * mean;
    float inv  = rsqrtf(var + 1e-5f);
    #pragma unroll
    for (int i = 0; i < 3; ++i) {
        int c = lane + i * 64;
        xp[c] = (v[i] - mean) * inv * g[c] + b[c];
    }
}

// ---------------------------------------------------------------- (b,pix,c) -> (b,c,pix)
__global__ __launch_bounds__(256) void bpc_to_bcp(
    const float* __restrict__ src, float* __restrict__ dst)
{
    __shared__ float tile[32][33];
    const int b = blockIdx.z;
    const int n0 = blockIdx.x * 32, c0 = blockIdx.y * 32;
    const int tx = threadIdx.x % 32, ty = threadIdx.x / 32;
    #pragma unroll
    for (int i = 0; i < 32; i += 8) {
        int n = n0 + ty + i, c = c0 + tx;
        if (n < NPIX) tile[ty + i][tx] = src[((size_t)b * NPIX + n) * C192 + c];
    }
    __syncthreads();
    #pragma unroll
    for (int i = 0; i < 32; i += 8) {
        int c = c0 + ty + i, n = n0 + tx;
        if (n < NPIX) dst[((size_t)b * C192 + c) * NPIX + n] = tile[tx][ty + i];
    }
}

// ---------------------------------------------------------------- launch
extern "C" void kernel_launch(void* const* d_in, const int* in_sizes, int n_in,
                              void* d_out, int out_size, void* d_ws, size_t ws_size,
                              hipStream_t stream)
{
    const float* x0 = (const float*)d_in[0];
    const float* x1 = (const float*)d_in[1];
    const float* x2 = (const float*)d_in[2];
    const float* z0 = (const float*)d_in[3];
    const float* z1 = (const float*)d_in[4];
    const float* z2 = (const float*)d_in[5];
    const float* conv1_w = (const float*)d_in[6];
    const float* conv3_w = (const float*)d_in[7];
    const float* conv2_w = (const float*)d_in[8];
    const float* bn1_g = (const float*)d_in[9];
    const float* bn1_b = (const float*)d_in[10];
    const float* bn1_m = (const float*)d_in[11];
    const float* bn1_v = (const float*)d_in[12];
    const float* bn2_g = (const float*)d_in[13];
    const float* bn2_b = (const float*)d_in[14];
    const float* bn2_m = (const float*)d_in[15];
    const float* bn2_v = (const float*)d_in[16];
    const float* bn3_g = (const float*)d_in[17];
    const float* bn3_b = (const float*)d_in[18];
    const float* bn3_m = (const float*)d_in[19];
    const float* bn3_v = (const float*)d_in[20];
    const float* row_embed = (const float*)d_in[21];
    const float* col_embed = (const float*)d_in[22];
    const float* t_wq = (const float*)d_in[23];
    const float* t_bq = (const float*)d_in[24];
    const float* t_wk = (const float*)d_in[25];
    const float* t_bk = (const float*)d_in[26];
    const float* t_wv = (const float*)d_in[27];
    const float* t_bv = (const float*)d_in[28];
    const float* t_wo = (const float*)d_in[29];
    const float* t_bo = (const float*)d_in[30];
    const float* t_ln1_g = (const float*)d_in[31];
    const float* t_ln1_b = (const float*)d_in[32];
    const float* t_ln2_g = (const float*)d_in[33];
    const float* t_ln2_b = (const float*)d_in[34];
    const float* t_ff1_w = (const float*)d_in[35];
    const float* t_ff1_b = (const float*)d_in[36];
    const float* t_ff2_w = (const float*)d_in[37];
    const float* t_ff2_b = (const float*)d_in[38];
    const float* convloc_w = (const float*)d_in[39];
    const float* convloc_b = (const float*)d_in[40];
    const float* convloc_gn_g = (const float*)d_in[41];
    const float* convloc_gn_b = (const float*)d_in[42];
    const float* loc_out_w = (const float*)d_in[43];
    const float* loc_out_b = (const float*)d_in[44];
    const float* convcls_w = (const float*)d_in[45];
    const float* convcls_b = (const float*)d_in[46];
    const float* convcls_gn_g = (const float*)d_in[47];
    const float* convcls_gn_b = (const float*)d_in[48];
    const float* cls1_w = (const float*)d_in[49];
    const float* cls1_b = (const float*)d_in[50];
    const float* cls2_w = (const float*)d_in[51];
    const float* cls2_b = (const float*)d_in[52];
    const int*   mask_size = (const int*)d_in[53];
    float* out = (float*)d_out;

    // workspace layout (floats)
    const size_t SZ_X = (size_t)NB * 384 * 625;   // 15,360,000
    const size_t SZ_S = (size_t)SEQM * C192;      // 2,076,672
    float* ws   = (float*)d_ws;
    float* Abuf = ws;
    float* res1 = Abuf + SZ_X;
    float* res2 = res1 + SZ_S;
    float* outb = res2 + SZ_S;
    float* qb   = outb + SZ_S;
    float* kb   = qb + SZ_S;
    float* vb   = kb + SZ_S;
    float* ob   = vb + SZ_S;
    float* resT = ob + SZ_S;
    float* y0   = resT + SZ_S;
    float* y1   = y0 + SZ_S;
    float* pbuf = qb;      // 2 partial buffers alias qb+kb (free in stage A / towers)

    // split-weight region (ushort), after y1
    unsigned short* UB = (unsigned short*)(y1 + SZ_S);
    size_t o = 0;
    unsigned short* cw1h = UB + o; o += 663552; unsigned short* cw1l = UB + o; o += 663552;
    unsigned short* cw3h = UB + o; o += 663552; unsigned short* cw3l = UB + o; o += 663552;
    unsigned short* cw2h = UB + o; o += 442368; unsigned short* cw2l = UB + o; o += 442368;
    unsigned short* cwlh = UB + o; o += 995328; unsigned short* cwll = UB + o; o += 995328;
    unsigned short* cwch = UB + o; o += 995328; unsigned short* cwcl = UB + o; o += 995328;
    unsigned short* twqh = UB + o; o += 73728;  unsigned short* twql = UB + o; o += 73728;
    unsigned short* twkh = UB + o; o += 73728;  unsigned short* twkl = UB + o; o += 73728;
    unsigned short* twvh = UB + o; o += 73728;  unsigned short* twvl = UB + o; o += 73728;
    unsigned short* twoh = UB + o; o += 73728;  unsigned short* twol = UB + o; o += 73728;
    unsigned short* tf1h = UB + o; o += 294912; unsigned short* tf1l = UB + o; o += 294912;
    unsigned short* tf2h = UB + o; o += 294912; unsigned short* tf2l = UB + o; o += 294912;

    // ---------------- weight pre-split (graph-safe, every launch)
    split_conv_w<384, 192><<<324, 256, 0, stream>>>(conv1_w, cw1h, cw1l);
    split_conv_w<384, 192><<<324, 256, 0, stream>>>(conv3_w, cw3h, cw3l);
    split_conv_w<256, 192><<<216, 256, 0, stream>>>(conv2_w, cw2h, cw2l);
    split_conv_w<192, 576><<<486, 256, 0, stream>>>(convloc_w, cwlh, cwll);
    split_conv_w<192, 576><<<486, 256, 0, stream>>>(convcls_w, cwch, cwcl);
    split_gemm_w<<<36, 256, 0, stream>>>(t_wq, twqh, twql, 384, 192);
    split_gemm_w<<<36, 256, 0, stream>>>(t_wk, twkh, twkl, 384, 192);
    split_gemm_w<<<36, 256, 0, stream>>>(t_wv, twvh, twvl, 384, 192);
    split_gemm_w<<<36, 256, 0, stream>>>(t_wo, twoh, twol, 384, 192);
    split_gemm_w<<<144, 256, 0, stream>>>(t_ff1_w, tf1h, tf1l, 1536, 192);
    split_gemm_w<<<144, 256, 0, stream>>>(t_ff2_w, tf2h, tf2l, 384, 768);

    const dim3 cgrid(NPIX, 3, 2);
    const int  rgrid = SEQM * 48 / 256;
    const dim3 tgrid(6, 6, NB);

    // ---------------- stage A: xcorr -> conv s2 -> BN -> ReLU  => (b,pix,c)
    xcorr_kernel<<<NB * 384, 256, 0, stream>>>(x0, z0, Abuf);
    conv_mfma<384, 2, 25, false><<<cgrid, 256, 0, stream>>>(Abuf, cw1h, cw1l, 192, 0, pbuf);
    reduce_bn_relu<<<rgrid, 256, 0, stream>>>(pbuf, bn1_g, bn1_b, bn1_m, bn1_v, res1);

    xcorr_kernel<<<NB * 384, 256, 0, stream>>>(x1, z1, Abuf);
    conv_mfma<384, 2, 25, false><<<cgrid, 256, 0, stream>>>(Abuf, cw3h, cw3l, 192, 0, pbuf);
    reduce_bn_relu<<<rgrid, 256, 0, stream>>>(pbuf, bn3_g, bn3_b, bn3_m, bn3_v, res2);

    xcorr_kernel<<<NB * 256, 256, 0, stream>>>(x2, z2, Abuf);
    conv_mfma<256, 2, 25, false><<<cgrid, 256, 0, stream>>>(Abuf, cw2h, cw2l, 192, 0, pbuf);
    reduce_bn_relu<<<rgrid, 256, 0, stream>>>(pbuf, bn2_g, bn2_b, bn2_m, bn2_v, outb);

    // ---------------- transformer (2 cross-attention layers), (b,pix,c)
    const int addpos_grid = (SEQM * C192 + 255) / 256;
    for (int li = 0; li < 2; ++li) {
        const float* mem = (li == 0) ? res1 : res2;
        const float* bq = t_bq + (size_t)li * C192;
        const float* bk = t_bk + (size_t)li * C192;
        const float* bv = t_bv + (size_t)li * C192;
        const float* bo = t_bo + (size_t)li * C192;
        const int noff = li * C192;

        addpos_kernel<<<addpos_grid, 256, 0, stream>>>(outb, row_embed, col_embed, qb);
        addpos_kernel<<<addpos_grid, 256, 0, stream>>>(mem,  row_embed, col_embed, kb);

        gemm_mfma<false><<<dim3(NPIX, 3), 256, 0, stream>>>(qb,  twqh, twql, bq, vb, 192, 192, 384, noff); // Qh
        gemm_mfma<false><<<dim3(NPIX, 3), 256, 0, stream>>>(kb,  twkh, twkl, bk, qb, 192, 192, 384, noff); // Kh
        gemm_mfma<false><<<dim3(NPIX, 3), 256, 0, stream>>>(mem, twvh, twvl, bv, kb, 192, 192, 384, noff); // Vh

        attn_kernel<<<NB * NH, 192, 0, stream>>>(vb, qb, kb, mask_size, ob);

        gemm_mfma<false><<<dim3(NPIX, 3), 256, 0, stream>>>(ob, twoh, twol, bo, qb, 192, 192, 384, noff);
        add_ln_kernel<<<SEQM / 4, 256, 0, stream>>>(outb, qb,
            t_ln1_g + (size_t)li * C192, t_ln1_b + (size_t)li * C192);

        gemm_mfma<true><<<dim3(NPIX, 12), 256, 0, stream>>>(outb, tf1h, tf1l,
            t_ff1_b + (size_t)li * 768, Abuf, 768, 192, 1536, li * 768);
        gemm_mfma<false><<<dim3(NPIX, 3), 256, 0, stream>>>(Abuf, tf2h, tf2l,
            t_ff2_b + (size_t)li * C192, qb, 192, 768, 384, noff);
        add_ln_kernel<<<SEQM / 4, 256, 0, stream>>>(outb, qb,
            t_ln2_g + (size_t)li * C192, t_ln2_b + (size_t)li * C192);
    }

    // ---------------- (b,pix,c) -> (b,c,pix) for the conv towers
    bpc_to_bcp<<<tgrid, 256, 0, stream>>>(outb, resT);

    // ---------------- loc tower
    {
        const float* yin = resT;
        float* ybufs[2] = { y0, y1 };
        for (int i = 0; i < 3; ++i) {
            conv_mfma<192, 1, 13, true><<<cgrid, 256, 0, stream>>>(yin, cwlh, cwll, 576, i * C192, pbuf);
            gn_reduce_relu<<<NB * 32, 256, 0, stream>>>(pbuf, convloc_b + (size_t)i * C192,
                convloc_gn_g + (size_t)i * C192, convloc_gn_b + (size_t)i * C192, ybufs[i & 1]);
            yin = ybufs[i & 1];
        }
        conv_s1_bias<4><<<dim3(NB, 1), 192, 0, stream>>>(yin, loc_out_w, loc_out_b, out);
    }

    // ---------------- cls tower
    {
        const float* yin = resT;
        float* ybufs[2] = { y1, y0 };
        for (int i = 0; i < 3; ++i) {
            conv_mfma<192, 1, 13, true><<<cgrid, 256, 0, stream>>>(yin, cwch, cwcl, 576, i * C192, pbuf);
            gn_reduce_relu<<<NB * 32, 256, 0, stream>>>(pbuf, convcls_b + (size_t)i * C192,
                convcls_gn_g + (size_t)i * C192, convcls_gn_b + (size_t)i * C192, ybufs[i & 1]);
            yin = ybufs[i & 1];
        }
        conv_s1_bias<2><<<dim3(NB, 1), 192, 0, stream>>>(yin, cls1_w, cls1_b, out + (size_t)NB * 4 * NPIX);
        conv_s1_bias<1><<<dim3(NB, 1), 192, 0, stream>>>(yin, cls2_w, cls2_b, out + (size_t)NB * 6 * NPIX);
    }
}